// Round 1
// 5111.786 us; speedup vs baseline: 1.6470x; 1.6470x over previous
//
#include <hip/hip_runtime.h>
#include <cstdint>

// Problem constants (fixed by the reference).
namespace {
constexpr int B = 4, T = 8192, C = 128, R = 64, S = 256, SO = 256, O = 256, L = 16;
constexpr float SQRT_HALF = 0.70710678118654752440f;
}

__device__ __forceinline__ float fsigm(float x) { return 1.0f / (1.0f + __expf(-x)); }
__device__ __forceinline__ float ftanh(float x) { return 1.0f - 2.0f / (1.0f + __expf(2.0f * x)); }

// Wave-uniform pin: threadIdx.x>>6-derived indices ARE uniform per wave, but
// divergence analysis can't prove it -> weight rows compile to per-lane
// global_load of the same address. readfirstlane makes them provably uniform
// so weight rows select s_load_dwordx* and FMAs take SGPR operands.
__device__ __forceinline__ int uni(int v) { return __builtin_amdgcn_readfirstlane(v); }

// x[b,r,t] = embed[tokens[b,t], r]
__global__ __launch_bounds__(256) void k_embed(const int* __restrict__ tokens,
                                               const float* __restrict__ embed,
                                               float* __restrict__ x) {
  int blk = blockIdx.x;            // B * (T/64) = 512
  int b = blk >> 7;
  int t0 = (blk & 127) << 6;
  int lane = threadIdx.x & 63;
  int w = threadIdx.x >> 6;        // wave handles 16 r's
  int t = t0 + lane;
  int tok = tokens[b * T + t];
  const float* e = embed + tok * R + w * 16;
  float* xp = x + ((size_t)b * R + w * 16) * T + t;
#pragma unroll
  for (int j = 0; j < 16; ++j) xp[(size_t)j * T] = e[j];
}

// cond[b, o, t] = cond_W[o,:] . features[b,:,t] + cond_b[o]   (o in [0,2048))
__global__ __launch_bounds__(256) void k_cond(const float* __restrict__ feat,
                                              const float* __restrict__ condW,
                                              const float* __restrict__ condb,
                                              float* __restrict__ cond_out) {
  int blk = blockIdx.x;            // 512
  int b = blk >> 7;
  int t0 = (blk & 127) << 6;
  int lane = threadIdx.x & 63;
  int w = threadIdx.x >> 6;
  int oc = blockIdx.y;             // 8 chunks of 256 outputs
  int o0 = uni(oc * 256 + w * 64); // this thread: 64 outputs (wave-uniform)
  int t = t0 + lane;
  float f[C];
  const float* fb = feat + (size_t)b * C * T + t;
#pragma unroll
  for (int k = 0; k < C; ++k) f[k] = fb[(size_t)k * T];
  float* outp = cond_out + ((size_t)b * (2 * R * L) + o0) * T + t;
  for (int j = 0; j < 64; ++j) {
    const float* wr = condW + (size_t)(o0 + j) * C;  // uniform row -> s_load_dwordx
    float acc = condb[o0 + j];
#pragma unroll
    for (int k = 0; k < C; ++k) acc = fmaf(wr[k], f[k], acc);
    outp[(size_t)j * T] = acc;
  }
}

// One WaveNet layer: ia = W0 x[t-d] + W1 x[t] + b (written to d_out),
// acts = tanh(.)*sigm(.), x_out = (res_W acts + res_b + x) * sqrt(0.5).
// last==1: only ia (the final x update is dead in the reference).
__global__ __launch_bounds__(256) void k_layer(const float* __restrict__ x_in,
                                               float* __restrict__ x_out,
                                               const float* __restrict__ cond,
                                               const float* __restrict__ dW,   // (128,64,2) for this layer
                                               const float* __restrict__ db,   // (128)
                                               const float* __restrict__ resW, // (64,64)
                                               const float* __restrict__ resb, // (64)
                                               float* __restrict__ ia_out,
                                               int l, int d, int last) {
  __shared__ float acts[64][64];   // [channel][t-in-tile], stride 64 -> 2-way (free)
  int blk = blockIdx.x;            // 512
  int b = blk >> 7;
  int t0 = (blk & 127) << 6;
  int lane = threadIdx.x & 63;
  int w = threadIdx.x >> 6;        // wave handles 16 gate-pairs
  int t = t0 + lane;
  const float* xb = x_in + (size_t)b * R * T;
  float xc[R], xp[R];
#pragma unroll
  for (int k = 0; k < R; ++k) xc[k] = xb[(size_t)k * T + t];
  if (t >= d) {
#pragma unroll
    for (int k = 0; k < R; ++k) xp[k] = xb[(size_t)k * T + t - d];
  } else {
#pragma unroll
    for (int k = 0; k < R; ++k) xp[k] = 0.0f;
  }
  const float* cnd = cond + (size_t)(b * L + l) * 128 * T + t;
  float* iao = ia_out + (size_t)(b * L + l) * 128 * T + t;
  int p0 = uni(w * 16);            // wave-uniform gate-pair base
  for (int p = p0; p < p0 + 16; ++p) {
    const float* w1 = dW + (size_t)p * 128;         // uniform row -> s_load
    const float* w2 = dW + (size_t)(p + 64) * 128;
    float a1 = db[p], a2 = db[p + 64];
#pragma unroll
    for (int k = 0; k < R; ++k) {
      a1 = fmaf(w1[2 * k], xp[k], a1);
      a1 = fmaf(w1[2 * k + 1], xc[k], a1);
      a2 = fmaf(w2[2 * k], xp[k], a2);
      a2 = fmaf(w2[2 * k + 1], xc[k], a2);
    }
    iao[(size_t)p * T] = a1;
    iao[(size_t)(p + 64) * T] = a2;
    a1 += cnd[(size_t)p * T];
    a2 += cnd[(size_t)(p + 64) * T];
    acts[p][lane] = ftanh(a1) * fsigm(a2);
  }
  __syncthreads();
  if (!last) {
    float areg[R];
#pragma unroll
    for (int k = 0; k < R; ++k) areg[k] = acts[k][lane];
    float* xo = x_out + (size_t)b * R * T + t;
    for (int o = p0; o < p0 + 16; ++o) {
      const float* wr = resW + (size_t)o * R;       // uniform row -> s_load
      float acc = resb[o];
#pragma unroll
      for (int k = 0; k < R; ++k) acc = fmaf(wr[k], areg[k], acc);
      // re-read x from global (L1 hit) to avoid dynamic register indexing
      xo[(size_t)o * T] = (acc + xb[(size_t)o * T + t]) * SQRT_HALF;
    }
  }
}

// skip_out[b,s,t] = sum_l ( skip_W[l,s,:] . acts_l[:,t] + skip_b[l,s] )
// acts recomputed from ia + cond (both already in d_out).
__global__ __launch_bounds__(256) void k_skip(const float* __restrict__ ia,
                                              const float* __restrict__ cond,
                                              const float* __restrict__ skipW, // (L,256,64)
                                              const float* __restrict__ skipb, // (L,256)
                                              float* __restrict__ skip_out) {
  int blk = blockIdx.x;            // 512
  int b = blk >> 7;
  int t0 = (blk & 127) << 6;
  int lane = threadIdx.x & 63;
  int w = threadIdx.x >> 6;
  int t = t0 + lane;
  int s0 = uni(w * 64);            // this thread: 64 skip channels (wave-uniform)
  float acc[64];
#pragma unroll
  for (int j = 0; j < 64; ++j) {
    float bs = 0.0f;
    for (int l = 0; l < L; ++l) bs += skipb[l * S + s0 + j];
    acc[j] = bs;
  }
  for (int l = 0; l < L; ++l) {
    const float* iab = ia + (size_t)(b * L + l) * 128 * T + t;
    const float* cnb = cond + (size_t)(b * L + l) * 128 * T + t;
    float areg[R];
#pragma unroll
    for (int k = 0; k < R; ++k) {
      float a1 = iab[(size_t)k * T] + cnb[(size_t)k * T];
      float a2 = iab[(size_t)(k + 64) * T] + cnb[(size_t)(k + 64) * T];
      areg[k] = ftanh(a1) * fsigm(a2);
    }
    const float* sw = skipW + (size_t)l * S * R + (size_t)s0 * R;
#pragma unroll
    for (int j = 0; j < 64; ++j) {
      const float* wr = sw + (size_t)j * R;          // uniform row -> s_load
      float a = acc[j];
#pragma unroll
      for (int k = 0; k < R; ++k) a = fmaf(wr[k], areg[k], a);
      acc[j] = a;
    }
  }
  float* sp = skip_out + ((size_t)b * S + s0) * T + t;
#pragma unroll
  for (int j = 0; j < 64; ++j) sp[(size_t)j * T] = acc[j];
}

// out = shift_right( Wend @ relu( Wout @ relu(skip) ) )
__global__ __launch_bounds__(256) void k_head(const float* __restrict__ skip_in,
                                              const float* __restrict__ Wout, // (256,256)
                                              const float* __restrict__ Wend, // (256,256)
                                              float* __restrict__ out) {
  __shared__ float hbuf[SO][64];   // 64 KB
  int blk = blockIdx.x;            // 512
  int b = blk >> 7;
  int t0 = (blk & 127) << 6;
  int lane = threadIdx.x & 63;
  int w = threadIdx.x >> 6;
  int t = t0 + lane;
  int g0 = uni(w * 64);            // this thread: 64 outputs of each stage (uniform)
  float acc[64];
#pragma unroll
  for (int j = 0; j < 64; ++j) acc[j] = 0.0f;
  for (int c = 0; c < 4; ++c) {    // K chunks of 64
    float areg[64];
    const float* sp = skip_in + ((size_t)b * S + c * 64) * T + t;
#pragma unroll
    for (int k = 0; k < 64; ++k) areg[k] = fmaxf(sp[(size_t)k * T], 0.0f);
#pragma unroll
    for (int j = 0; j < 64; ++j) {
      const float* wr = Wout + (size_t)(g0 + j) * S + c * 64;  // uniform row -> s_load
      float a = acc[j];
#pragma unroll
      for (int k = 0; k < 64; ++k) a = fmaf(wr[k], areg[k], a);
      acc[j] = a;
    }
  }
#pragma unroll
  for (int j = 0; j < 64; ++j) hbuf[g0 + j][lane] = fmaxf(acc[j], 0.0f);
  __syncthreads();
#pragma unroll
  for (int j = 0; j < 64; ++j) acc[j] = 0.0f;
  for (int c = 0; c < 4; ++c) {
    float areg[64];
#pragma unroll
    for (int k = 0; k < 64; ++k) areg[k] = hbuf[c * 64 + k][lane];
#pragma unroll
    for (int j = 0; j < 64; ++j) {
      const float* wr = Wend + (size_t)(g0 + j) * SO + c * 64; // uniform row -> s_load
      float a = acc[j];
#pragma unroll
      for (int k = 0; k < 64; ++k) a = fmaf(wr[k], areg[k], a);
      acc[j] = a;
    }
  }
  float* ob = out + ((size_t)b * O + g0) * T;
  if (t + 1 < T) {
#pragma unroll
    for (int j = 0; j < 64; ++j) ob[(size_t)j * T + t + 1] = acc[j];
  }
  if (t0 == 0 && lane == 0) {      // zero frame at t=0
#pragma unroll
    for (int j = 0; j < 64; ++j) ob[(size_t)j * T] = 0.0f;
  }
}

extern "C" void kernel_launch(void* const* d_in, const int* in_sizes, int n_in,
                              void* d_out, int out_size, void* d_ws, size_t ws_size,
                              hipStream_t stream) {
  const float* features   = (const float*)d_in[0];
  const int*   tokens     = (const int*)d_in[1];
  const float* embed      = (const float*)d_in[2];
  const float* cond_W     = (const float*)d_in[3];
  const float* cond_b     = (const float*)d_in[4];
  const float* dilate_W   = (const float*)d_in[5];
  const float* dilate_b   = (const float*)d_in[6];
  const float* res_W      = (const float*)d_in[7];
  const float* res_b      = (const float*)d_in[8];
  const float* skip_W     = (const float*)d_in[9];
  const float* skip_b     = (const float*)d_in[10];
  const float* conv_out_W = (const float*)d_in[11];
  const float* conv_end_W = (const float*)d_in[12];

  // d_out regions: out (B*O*T), in_acts (B*L*128*T), cond (B*L*128*T)
  float* out  = (float*)d_out;
  float* ia   = out + (size_t)B * O * T;
  float* cond = ia + (size_t)B * L * 2 * R * T;

  // workspace: x ping-pong (2 x 8 MB) + skip_out (32 MB) = 48 MB
  float* xa   = (float*)d_ws;
  float* xb   = xa + (size_t)B * R * T;
  float* skip = xb + (size_t)B * R * T;

  dim3 blk(256);
  int nblk = B * (T / 64);  // 512

  k_embed<<<nblk, blk, 0, stream>>>(tokens, embed, xa);
  k_cond<<<dim3(nblk, 8), blk, 0, stream>>>(features, cond_W, cond_b, cond);

  static const int DIL[L] = {1, 2, 4, 8, 16, 32, 64, 128, 256, 1, 2, 4, 8, 16, 32, 64};
  float* xcur = xa;
  float* xnxt = xb;
  for (int l = 0; l < L; ++l) {
    int lr = (l < L - 1) ? l : 0;  // resW/resb unused when last
    k_layer<<<nblk, blk, 0, stream>>>(xcur, xnxt, cond,
                                      dilate_W + (size_t)l * 128 * 64 * 2,
                                      dilate_b + (size_t)l * 128,
                                      res_W + (size_t)lr * 64 * 64,
                                      res_b + (size_t)lr * 64,
                                      ia, l, DIL[l], (l == L - 1) ? 1 : 0);
    float* tmp = xcur; xcur = xnxt; xnxt = tmp;
  }
  k_skip<<<nblk, blk, 0, stream>>>(ia, cond, skip_W, skip_b, skip);
  k_head<<<nblk, blk, 0, stream>>>(skip, conv_out_W, conv_end_W, out);
}